// Round 6
// baseline (393.742 us; speedup 1.0000x reference)
//
#include <hip/hip_runtime.h>
#include <hip/hip_bf16.h>
#include <stdint.h>

typedef int int4v __attribute__((ext_vector_type(4)));     // MFMA i8 operands / i32 acc
typedef short short8 __attribute__((ext_vector_type(8)));
typedef float f32x4 __attribute__((ext_vector_type(4)));

#define D_IN   784
#define KP1    832      // 13 * 64, zero-padded K for layer 1
#define D_H    4096
#define D_OUT  10
#define MROWS  16384

// ---------------- ws layout (bytes) ----------------
// [0,16)                 double sums[2]  (sum|w1|, sum|w2|)  -- zeroed per launch
// [256, +65536)          float a1[16384]      (per-row combined dequant scale)
// [65792, +65536)        float ss[16384]      (per-row sum t^2; atomic, zeroed)
// [131328, +65536)       u32   mx[16384]      (per-row max t bits; atomic, zeroed)
// [196864, +65536)       i32   w2p[1024][16]  (ternary w2: 4 k-bytes per dword, j-major)
// [262400, +3407872)     int8  w1q[4096][832]
// [3670272, +13631488)   int8  xq[16384][832]
// [17301760, ...)        int16 h16[rpc][4096] (raw integer GEMM accumulators)
#define FIXED_BYTES 17301760

__device__ __forceinline__ void gload16(const void* g, void* l) {
  __builtin_amdgcn_global_load_lds(
      (__attribute__((address_space(1))) void*)(uintptr_t)g,
      (__attribute__((address_space(3))) void*)l, 16, 0, 0);
}

__global__ void kAbsSum(const float* __restrict__ w, int n, double* __restrict__ dst) {
  __shared__ float sm[4];
  float s = 0.f;
  for (int i = blockIdx.x * blockDim.x + threadIdx.x; i < n; i += gridDim.x * blockDim.x)
    s += fabsf(w[i]);
#pragma unroll
  for (int off = 32; off; off >>= 1) s += __shfl_xor(s, off);
  int lane = threadIdx.x & 63, wid = threadIdx.x >> 6;
  if (lane == 0) sm[wid] = s;
  __syncthreads();
  if (threadIdx.x == 0) atomicAdd(dst, (double)(sm[0] + sm[1] + sm[2] + sm[3]));
}

// wave per row; float4 reads, char4 writes. Pads [784,832) written as 0 every call.
__global__ void kQuantW1(const float* __restrict__ w1, signed char* __restrict__ wq,
                         const double* __restrict__ sums) {
  int row = blockIdx.x * 4 + (threadIdx.x >> 6);
  int lane = threadIdx.x & 63;
  float mw = fmaxf((float)(sums[0] / (double)(D_H * D_IN)), 1e-5f);
  float wscale = 1.0f / mw;
  const float* wr = w1 + (size_t)row * D_IN;
#pragma unroll
  for (int i = 0; i < 4; ++i) {
    int k4 = i * 256 + lane * 4;
    if (k4 >= KP1) continue;
    f32x4 v = {};
    if (k4 < D_IN) v = *(const f32x4*)(wr + k4);      // 784 % 4 == 0: exact boundary
    char out[4];
#pragma unroll
    for (int j = 0; j < 4; ++j) {
      float t = fminf(fmaxf(rintf(v[j] * wscale), -1.f), 1.f);
      out[j] = (char)(int)t;
    }
    *(char4*)(wq + (size_t)row * KP1 + k4) = *(char4*)out;
  }
}

// w2p[k4][j] dword = ternary bytes {w2q[k4*4+0..3][j]}; j in [10,16) zero.
__global__ void kQuantW2(const float* __restrict__ w2, int* __restrict__ w2p,
                         const double* __restrict__ sums) {
  int idx = blockIdx.x * blockDim.x + threadIdx.x;   // [0, 16384)
  if (idx >= 1024 * 16) return;
  int k4 = idx >> 4, j = idx & 15;
  float mw = fmaxf((float)(sums[1] / (double)(D_OUT * D_H)), 1e-5f);
  float wscale = 1.0f / mw;
  int packed = 0;
  if (j < D_OUT) {
#pragma unroll
    for (int b = 0; b < 4; ++b) {
      float v = w2[(size_t)j * D_H + k4 * 4 + b] * wscale;
      int t = (int)fminf(fmaxf(rintf(v), -1.f), 1.f);
      packed |= (t & 255) << (8 * b);
    }
  }
  w2p[idx] = packed;
}

// wave per row; float4 reads, char4 int8 writes; a1[row] = (1/scale)*wdeq.
__global__ void kQuantX(const float* __restrict__ x, signed char* __restrict__ xq,
                        float* __restrict__ a1, const double* __restrict__ sums) {
  int row = blockIdx.x * 4 + (threadIdx.x >> 6);
  int lane = threadIdx.x & 63;
  const float* xr = x + (size_t)row * D_IN;
  f32x4 v[4];
  float ss = 0.f, mx = 0.f;
#pragma unroll
  for (int i = 0; i < 4; ++i) {
    int k4 = i * 256 + lane * 4;
    v[i] = (f32x4){};
    if (k4 < D_IN) v[i] = *(const f32x4*)(xr + k4);
#pragma unroll
    for (int j = 0; j < 4; ++j) {
      ss += v[i][j] * v[i][j];
      mx = fmaxf(mx, fabsf(v[i][j]));
    }
  }
#pragma unroll
  for (int off = 32; off; off >>= 1) {
    ss += __shfl_xor(ss, off);
    mx = fmaxf(mx, __shfl_xor(mx, off));
  }
  float rinv = 1.0f / sqrtf(ss / (float)D_IN + 1e-6f);
  float mq = fmaxf(mx * rinv, 1e-5f);   // max|xn| == max|x|*rinv (monotone f32 mult)
  float scale = 127.0f / mq;
  if (lane == 0) {
    float mw = fmaxf((float)(sums[0] / (double)(D_H * D_IN)), 1e-5f);
    float wdeq = 1.0f / (1.0f / mw);    // replicate reference double-rounding
    a1[row] = (1.0f / scale) * wdeq;
  }
#pragma unroll
  for (int i = 0; i < 4; ++i) {
    int k4 = i * 256 + lane * 4;
    if (k4 >= KP1) continue;
    char out[4];
#pragma unroll
    for (int j = 0; j < 4; ++j) {
      float t = rintf(v[i][j] * rinv * scale);
      t = fminf(fmaxf(t, -128.f), 127.f);
      out[j] = (char)(int)t;
    }
    *(char4*)(xq + (size_t)row * KP1 + k4) = *(char4*)out;
  }
}

// m97-structure GEMM, i8 (unchanged loop) + FUSED per-row stats in the epilogue.
__global__ __launch_bounds__(256) void kGemm1(
    const signed char* __restrict__ xq,
    const signed char* __restrict__ wq,
    const float* __restrict__ a1, const float* __restrict__ b1,
    float* __restrict__ ssArr, unsigned int* __restrict__ mxArr,
    short* __restrict__ h16) {
  __shared__ __align__(16) char lA[128 * 64];   // 8 KB
  __shared__ __align__(16) char lB[128 * 64];   // 8 KB
  int tid = threadIdx.x;
  int nwg = gridDim.x;                 // multiple of 32 -> XCD swizzle bijective
  int cpx = nwg >> 3;
  int bid = blockIdx.x;
  int swz = (bid & 7) * cpx + (bid >> 3);
  const int nbN = D_H / 128;           // 32
  int mb = swz / nbN, nb = swz - mb * nbN;
  int RM = mb * 128, CN = nb * 128;
  int lane = tid & 63, wid = tid >> 6;
  int wr = wid >> 1, wc = wid & 1;

  int4v acc[4][4] = {};

  for (int kt = 0; kt < KP1 / 64; ++kt) {   // 13 K-steps
    int k0 = kt * 64;
#pragma unroll
    for (int it = 0; it < 2; ++it) {
      int idx = it * 256 + tid;        // 0..511 ; LDS dest linear in lane (gload_lds rule)
      int row = idx >> 2, c16 = idx & 3;
      gload16(xq + (size_t)(RM + row) * KP1 + k0 + c16 * 16, &lA[idx * 16]);
      gload16(wq + (size_t)(CN + row) * KP1 + k0 + c16 * 16, &lB[idx * 16]);
    }
    __syncthreads();
    {
      int kc = (lane >> 4) * 16;       // A/B frag: row=lane&15, k=(lane>>4)*16+j
      int4v af[4], bg[4];
#pragma unroll
      for (int m = 0; m < 4; ++m) {
        int row = wr * 64 + m * 16 + (lane & 15);
        af[m] = *(const int4v*)&lA[row * 64 + kc];
      }
#pragma unroll
      for (int n = 0; n < 4; ++n) {
        int col = wc * 64 + n * 16 + (lane & 15);
        bg[n] = *(const int4v*)&lB[col * 64 + kc];
      }
#pragma unroll
      for (int m = 0; m < 4; ++m)
#pragma unroll
        for (int n = 0; n < 4; ++n)
          acc[m][n] = __builtin_amdgcn_mfma_i32_16x16x64_i8(af[m], bg[n], acc[m][n],
                                                            0, 0, 0);
    }
    __syncthreads();
  }

  // epilogue: write raw ints; fused row stats (t = relu(fma(acc, a1, b1)))
  float bcol[4];
#pragma unroll
  for (int n = 0; n < 4; ++n)
    bcol[n] = b1[CN + wc * 64 + n * 16 + (lane & 15)];
#pragma unroll
  for (int m = 0; m < 4; ++m) {
    int rbase = RM + wr * 64 + m * 16 + (lane >> 4) * 4;
#pragma unroll
    for (int r = 0; r < 4; ++r) {
      int grow = rbase + r;
      float a1r = a1[grow];
      float pss = 0.f, pmx = 0.f;
#pragma unroll
      for (int n = 0; n < 4; ++n) {
        int col = CN + wc * 64 + n * 16 + (lane & 15);
        int av = acc[m][n][r];
        h16[(size_t)grow * D_H + col] = (short)av;
        float t = fmaxf(__builtin_fmaf((float)av, a1r, bcol[n]), 0.f);
        pss = __builtin_fmaf(t, t, pss);
        pmx = fmaxf(pmx, t);
      }
#pragma unroll
      for (int off = 1; off < 16; off <<= 1) {      // reduce within 16-lane group
        pss += __shfl_xor(pss, off);
        pmx = fmaxf(pmx, __shfl_xor(pmx, off));
      }
      if ((lane & 15) == 0) {
        atomicAdd(&ssArr[grow], pss);
        atomicMax(&mxArr[grow], __float_as_uint(pmx));   // t >= 0: bits monotone
      }
    }
  }
}

// layer 2: one wave per row, SINGLE PASS, no per-lane arrays (no spill).
// h reconstructed exactly as in epilogue; ternary dot in exact integer arithmetic.
__global__ __launch_bounds__(1024) void kLayer2(
    const short* __restrict__ h16, const float* __restrict__ a1,
    const float* __restrict__ ssArr, const unsigned int* __restrict__ mxArr,
    const float* __restrict__ b1, const int* __restrict__ w2p,
    const float* __restrict__ b2, const double* __restrict__ sums,
    float* __restrict__ out) {
  int wid = threadIdx.x >> 6, lane = threadIdx.x & 63;
  int row = blockIdx.x * 16 + wid;
  float a1r = a1[row];
  float rinv = 1.0f / sqrtf(ssArr[row] / (float)D_H + 1e-6f);
  float mq = fmaxf(__uint_as_float(mxArr[row]) * rinv, 1e-5f);
  float scale = 127.0f / mq;
  const short* hr = h16 + (size_t)row * D_H;
  int acc[10] = {0, 0, 0, 0, 0, 0, 0, 0, 0, 0};
#pragma unroll
  for (int c = 0; c < 8; ++c) {
    int k0 = c * 512 + lane * 8;
    short8 v = *(const short8*)(hr + k0);
    f32x4 b1a = *(const f32x4*)(b1 + k0);
    f32x4 b1b = *(const f32x4*)(b1 + k0 + 4);
    int tq[8];
#pragma unroll
    for (int j = 0; j < 8; ++j) {
      float fi = (float)(int)v[j];
      float bb = (j < 4) ? b1a[j] : b1b[j - 4];
      float t = fmaxf(__builtin_fmaf(fi, a1r, bb), 0.f);   // == epilogue t exactly
      float xn = t * rinv;
      float tf = rintf(xn * scale);
      tf = fminf(fmaxf(tf, -128.f), 127.f);
      tq[j] = (int)tf;
    }
    int tp0 = (tq[0] & 255) | ((tq[1] & 255) << 8) | ((tq[2] & 255) << 16) | (tq[3] << 24);
    int tp1 = (tq[4] & 255) | ((tq[5] & 255) << 8) | ((tq[6] & 255) << 16) | (tq[7] << 24);
    int k4 = c * 128 + lane * 2;
    const int* w0 = w2p + k4 * 16;
    const int* w1 = w2p + (k4 + 1) * 16;
#if __has_builtin(__builtin_amdgcn_sdot4)
#pragma unroll
    for (int j = 0; j < 10; ++j) {
      acc[j] = __builtin_amdgcn_sdot4(tp0, w0[j], acc[j], false);
      acc[j] = __builtin_amdgcn_sdot4(tp1, w1[j], acc[j], false);
    }
#else
#pragma unroll
    for (int j = 0; j < 10; ++j) {
      int q0 = w0[j], q1 = w1[j];
#pragma unroll
      for (int b = 0; b < 4; ++b) {
        acc[j] += tq[b]     * (int)(signed char)((unsigned)q0 >> (8 * b));
        acc[j] += tq[4 + b] * (int)(signed char)((unsigned)q1 >> (8 * b));
      }
    }
#endif
  }
#pragma unroll
  for (int j = 0; j < 10; ++j)
#pragma unroll
    for (int off = 32; off; off >>= 1)
      acc[j] += __shfl_xor(acc[j], off);
  if (lane < 10) {
    float mw = fmaxf((float)(sums[1] / (double)(D_OUT * D_H)), 1e-5f);
    float wdeq = 1.0f / (1.0f / mw);
    int seli = 0;
#pragma unroll
    for (int j = 0; j < 10; ++j) seli = (lane == j) ? acc[j] : seli;  // static-index select
    float sel = (float)seli;          // exact: |sum| < 2^24
    out[(size_t)row * D_OUT + lane] = sel * (1.0f / scale) * wdeq + b2[lane];
  }
}

extern "C" void kernel_launch(void* const* d_in, const int* in_sizes, int n_in,
                              void* d_out, int out_size, void* d_ws, size_t ws_size,
                              hipStream_t stream) {
  const float* x  = (const float*)d_in[0];
  const float* w1 = (const float*)d_in[1];
  const float* b1 = (const float*)d_in[2];
  const float* w2 = (const float*)d_in[3];
  const float* b2 = (const float*)d_in[4];
  float* out = (float*)d_out;

  char* p = (char*)d_ws;
  double* sums        = (double*)p;
  float* a1           = (float*)(p + 256);
  float* ssArr        = (float*)(p + 65792);
  unsigned int* mxArr = (unsigned int*)(p + 131328);
  int* w2p            = (int*)(p + 196864);
  signed char* w1q    = (signed char*)(p + 262400);
  signed char* xq8    = (signed char*)(p + 3670272);
  short* h16          = (short*)(p + FIXED_BYTES);

  // size the h chunk from the ACTUAL workspace (round to multiple of 128 rows)
  size_t avail = (ws_size > FIXED_BYTES) ? ws_size - FIXED_BYTES : 0;
  int rpc = (int)(avail / ((size_t)D_H * sizeof(short)));
  rpc = (rpc / 128) * 128;
  if (rpc > MROWS) rpc = MROWS;
  if (rpc < 128) rpc = 128;

  hipMemsetAsync(sums, 0, 16, stream);
  hipMemsetAsync(p + 65792, 0, 131072, stream);   // ss + mx
  kAbsSum<<<1024, 256, 0, stream>>>(w1, D_H * D_IN, &sums[0]);
  kAbsSum<<<64, 256, 0, stream>>>(w2, D_OUT * D_H, &sums[1]);
  kQuantW1<<<D_H / 4, 256, 0, stream>>>(w1, w1q, sums);
  kQuantW2<<<64, 256, 0, stream>>>(w2, w2p, sums);
  kQuantX<<<MROWS / 4, 256, 0, stream>>>(x, xq8, a1, sums);

  for (int r0 = 0; r0 < MROWS; r0 += rpc) {
    int rc = (MROWS - r0 < rpc) ? (MROWS - r0) : rpc;   // multiple of 128
    kGemm1<<<(rc / 128) * (D_H / 128), 256, 0, stream>>>(
        xq8 + (size_t)r0 * KP1, w1q, a1 + r0, b1, ssArr + r0, mxArr + r0, h16);
    kLayer2<<<rc / 16, 1024, 0, stream>>>(h16, a1 + r0, ssArr + r0, mxArr + r0,
                                          b1, w2p, b2, sums, out + (size_t)r0 * D_OUT);
  }
}

// Round 8
// 333.775 us; speedup vs baseline: 1.1797x; 1.1797x over previous
//
#include <hip/hip_runtime.h>
#include <hip/hip_bf16.h>
#include <stdint.h>

typedef int int4v __attribute__((ext_vector_type(4)));     // MFMA i8 operands / i32 acc
typedef int int2v __attribute__((ext_vector_type(2)));
typedef short short8 __attribute__((ext_vector_type(8)));
typedef float f32x4 __attribute__((ext_vector_type(4)));

#define D_IN   784
#define KP1    832      // 13 * 64, zero-padded K for layer 1
#define D_H    4096
#define D_OUT  10
#define MROWS  16384

// ---------------- ws layout (bytes) ----------------
// [0,16)                 double sums[2]  (sum|w1|, sum|w2|)  -- zeroed per launch
// [256, +65536)          float a1[16384]      (per-row combined dequant scale)
// [65792, +65536)        float ss[16384]      (per-row sum t^2; atomic, zeroed)
// [131328, +65536)       u32   mx[16384]      (per-row max t bits; atomic, zeroed)
// [196864, +40960)       i32   w2t[10][1024]  (ternary w2, j-major, 4 k-bytes/dword)
// [262400, +3407872)     int8  w1q[4096][832]
// [3670272, +13631488)   int8  xq[16384][832]
// [17301760, ...)        int16 h16[rpc][4096] (raw integer GEMM accumulators)
#define FIXED_BYTES 17301760

__device__ __forceinline__ void gload16(const void* g, void* l) {
  __builtin_amdgcn_global_load_lds(
      (__attribute__((address_space(1))) void*)(uintptr_t)g,
      (__attribute__((address_space(3))) void*)l, 16, 0, 0);
}

__global__ void kAbsSum(const float* __restrict__ w, int n, double* __restrict__ dst) {
  __shared__ float sm[4];
  float s = 0.f;
  for (int i = blockIdx.x * blockDim.x + threadIdx.x; i < n; i += gridDim.x * blockDim.x)
    s += fabsf(w[i]);
#pragma unroll
  for (int off = 32; off; off >>= 1) s += __shfl_xor(s, off);
  int lane = threadIdx.x & 63, wid = threadIdx.x >> 6;
  if (lane == 0) sm[wid] = s;
  __syncthreads();
  if (threadIdx.x == 0) atomicAdd(dst, (double)(sm[0] + sm[1] + sm[2] + sm[3]));
}

// wave per row; float4 reads, char4 writes. Pads [784,832) written as 0 every call.
__global__ void kQuantW1(const float* __restrict__ w1, signed char* __restrict__ wq,
                         const double* __restrict__ sums) {
  int row = blockIdx.x * 4 + (threadIdx.x >> 6);
  int lane = threadIdx.x & 63;
  float mw = fmaxf((float)(sums[0] / (double)(D_H * D_IN)), 1e-5f);
  float wscale = 1.0f / mw;
  const float* wr = w1 + (size_t)row * D_IN;
#pragma unroll
  for (int i = 0; i < 4; ++i) {
    int k4 = i * 256 + lane * 4;
    if (k4 >= KP1) continue;
    f32x4 v = {};
    if (k4 < D_IN) v = *(const f32x4*)(wr + k4);      // 784 % 4 == 0: exact boundary
    char out[4];
#pragma unroll
    for (int j = 0; j < 4; ++j) {
      float t = fminf(fmaxf(rintf(v[j] * wscale), -1.f), 1.f);
      out[j] = (char)(int)t;
    }
    *(char4*)(wq + (size_t)row * KP1 + k4) = *(char4*)out;
  }
}

// w2t[j][k4] dword = ternary bytes {w2q[k4*4+0..3][j]}; j-major so kLayer2 can
// stage coalesced-global -> linear-LDS with no transpose.
__global__ void kQuantW2(const float* __restrict__ w2, int* __restrict__ w2t,
                         const double* __restrict__ sums) {
  int idx = blockIdx.x * blockDim.x + threadIdx.x;   // [0, 10240)
  if (idx >= D_OUT * 1024) return;
  int j = idx >> 10, k4 = idx & 1023;
  float mw = fmaxf((float)(sums[1] / (double)(D_OUT * D_H)), 1e-5f);
  float wscale = 1.0f / mw;
  int packed = 0;
#pragma unroll
  for (int b = 0; b < 4; ++b) {
    float v = w2[(size_t)j * D_H + k4 * 4 + b] * wscale;
    int t = (int)fminf(fmaxf(rintf(v), -1.f), 1.f);
    packed |= (t & 255) << (8 * b);
  }
  w2t[idx] = packed;
}

// wave per row; float4 reads, char4 int8 writes; a1[row] = (1/scale)*wdeq.
__global__ void kQuantX(const float* __restrict__ x, signed char* __restrict__ xq,
                        float* __restrict__ a1, const double* __restrict__ sums) {
  int row = blockIdx.x * 4 + (threadIdx.x >> 6);
  int lane = threadIdx.x & 63;
  const float* xr = x + (size_t)row * D_IN;
  f32x4 v[4];
  float ss = 0.f, mx = 0.f;
#pragma unroll
  for (int i = 0; i < 4; ++i) {
    int k4 = i * 256 + lane * 4;
    v[i] = (f32x4){};
    if (k4 < D_IN) v[i] = *(const f32x4*)(xr + k4);
#pragma unroll
    for (int j = 0; j < 4; ++j) {
      ss += v[i][j] * v[i][j];
      mx = fmaxf(mx, fabsf(v[i][j]));
    }
  }
#pragma unroll
  for (int off = 32; off; off >>= 1) {
    ss += __shfl_xor(ss, off);
    mx = fmaxf(mx, __shfl_xor(mx, off));
  }
  float rinv = 1.0f / sqrtf(ss / (float)D_IN + 1e-6f);
  float mq = fmaxf(mx * rinv, 1e-5f);   // max|xn| == max|x|*rinv (monotone f32 mult)
  float scale = 127.0f / mq;
  if (lane == 0) {
    float mw = fmaxf((float)(sums[0] / (double)(D_H * D_IN)), 1e-5f);
    float wdeq = 1.0f / (1.0f / mw);    // replicate reference double-rounding
    a1[row] = (1.0f / scale) * wdeq;
  }
#pragma unroll
  for (int i = 0; i < 4; ++i) {
    int k4 = i * 256 + lane * 4;
    if (k4 >= KP1) continue;
    char out[4];
#pragma unroll
    for (int j = 0; j < 4; ++j) {
      float t = rintf(v[i][j] * rinv * scale);
      t = fminf(fmaxf(t, -128.f), 127.f);
      out[j] = (char)(int)t;
    }
    *(char4*)(xq + (size_t)row * KP1 + k4) = *(char4*)out;
  }
}

// i8 GEMM, 128x128 tile, BK=64, 4 waves, DOUBLE-BUFFERED LDS (2-phase):
// stage tile t+1 BEFORE computing tile t; ONE barrier per K-step whose auto
// vmcnt-drain is overlapped with this step's ds_read+MFMA. Fused row stats.
__global__ __launch_bounds__(256) void kGemm1(
    const signed char* __restrict__ xq,
    const signed char* __restrict__ wq,
    const float* __restrict__ a1, const float* __restrict__ b1,
    float* __restrict__ ssArr, unsigned int* __restrict__ mxArr,
    short* __restrict__ h16) {
  __shared__ __align__(16) char lA[2][128 * 64];   // 2 x 8 KB
  __shared__ __align__(16) char lB[2][128 * 64];   // 2 x 8 KB
  int tid = threadIdx.x;
  int nwg = gridDim.x;                 // multiple of 32 -> XCD swizzle bijective
  int cpx = nwg >> 3;
  int bid = blockIdx.x;
  int swz = (bid & 7) * cpx + (bid >> 3);
  const int nbN = D_H / 128;           // 32
  int mb = swz / nbN, nb = swz - mb * nbN;
  int RM = mb * 128, CN = nb * 128;
  int lane = tid & 63, wid = tid >> 6;
  int wr = wid >> 1, wc = wid & 1;

  // per-thread staging coords (idx, idx+256), row = idx>>2, 16B col = idx&3
  int i0 = tid, i1 = tid + 256;
  int r0s = i0 >> 2, c0s = (i0 & 3) * 16;
  int r1s = i1 >> 2, c1s = (i1 & 3) * 16;

#define STAGE(buf, kt)                                                          \
  {                                                                             \
    int k0_ = (kt) * 64;                                                        \
    gload16(xq + (size_t)(RM + r0s) * KP1 + k0_ + c0s, &lA[buf][i0 * 16]);      \
    gload16(wq + (size_t)(CN + r0s) * KP1 + k0_ + c0s, &lB[buf][i0 * 16]);      \
    gload16(xq + (size_t)(RM + r1s) * KP1 + k0_ + c1s, &lA[buf][i1 * 16]);      \
    gload16(wq + (size_t)(CN + r1s) * KP1 + k0_ + c1s, &lB[buf][i1 * 16]);      \
  }

  int4v acc[4][4] = {};

  STAGE(0, 0);
  __syncthreads();                       // auto vmcnt(0) drain: tile 0 resident

  for (int kt = 0; kt < KP1 / 64; ++kt) {   // 13 K-steps
    int cur = kt & 1;
    if (kt < KP1 / 64 - 1) STAGE(cur ^ 1, kt + 1);   // prefetch next tile
    {
      int kc = (lane >> 4) * 16;       // A/B frag: row=lane&15, k=(lane>>4)*16+j
      int4v af[4], bg[4];
#pragma unroll
      for (int m = 0; m < 4; ++m) {
        int row = wr * 64 + m * 16 + (lane & 15);
        af[m] = *(const int4v*)&lA[cur][row * 64 + kc];
      }
#pragma unroll
      for (int n = 0; n < 4; ++n) {
        int col = wc * 64 + n * 16 + (lane & 15);
        bg[n] = *(const int4v*)&lB[cur][col * 64 + kc];
      }
#pragma unroll
      for (int m = 0; m < 4; ++m)
#pragma unroll
        for (int n = 0; n < 4; ++n)
          acc[m][n] = __builtin_amdgcn_mfma_i32_16x16x64_i8(af[m], bg[n], acc[m][n],
                                                            0, 0, 0);
    }
    __syncthreads();   // single barrier: drains prefetch (overlapped w/ compute above)
  }
#undef STAGE

  // epilogue: write raw ints; fused row stats (t = relu(fma(acc, a1, b1)))
  float bcol[4];
#pragma unroll
  for (int n = 0; n < 4; ++n)
    bcol[n] = b1[CN + wc * 64 + n * 16 + (lane & 15)];
#pragma unroll
  for (int m = 0; m < 4; ++m) {
    int rbase = RM + wr * 64 + m * 16 + (lane >> 4) * 4;
#pragma unroll
    for (int r = 0; r < 4; ++r) {
      int grow = rbase + r;
      float a1r = a1[grow];
      float pss = 0.f, pmx = 0.f;
#pragma unroll
      for (int n = 0; n < 4; ++n) {
        int col = CN + wc * 64 + n * 16 + (lane & 15);
        int av = acc[m][n][r];
        h16[(size_t)grow * D_H + col] = (short)av;
        float t = fmaxf(__builtin_fmaf((float)av, a1r, bcol[n]), 0.f);
        pss = __builtin_fmaf(t, t, pss);
        pmx = fmaxf(pmx, t);
      }
#pragma unroll
      for (int off = 1; off < 16; off <<= 1) {      // reduce within 16-lane group
        pss += __shfl_xor(pss, off);
        pmx = fmaxf(pmx, __shfl_xor(pmx, off));
      }
      if ((lane & 15) == 0) {
        atomicAdd(&ssArr[grow], pss);
        atomicMax(&mxArr[grow], __float_as_uint(pmx));   // t >= 0: bits monotone
      }
    }
  }
}

// layer 2: one wave per row, single pass; w2 ternary staged in LDS (j-major,
// 40KB) -> 10x ds_read_b64 per c-iter at lane-stride 2 dwords (conflict-free),
// replacing the round-6 uncoalesced global loads. Exact int sdot4 accumulation.
__global__ __launch_bounds__(1024) void kLayer2(
    const short* __restrict__ h16, const float* __restrict__ a1,
    const float* __restrict__ ssArr, const unsigned int* __restrict__ mxArr,
    const float* __restrict__ b1, const int* __restrict__ w2t,
    const float* __restrict__ b2, const double* __restrict__ sums,
    float* __restrict__ out) {
  __shared__ int w2s[D_OUT * 1024];   // 40 KB
#pragma unroll
  for (int i = 0; i < D_OUT; ++i)     // coalesced global read, linear LDS write
    w2s[i * 1024 + threadIdx.x] = w2t[i * 1024 + threadIdx.x];
  __syncthreads();

  int wid = threadIdx.x >> 6, lane = threadIdx.x & 63;
  int row = blockIdx.x * 16 + wid;
  float a1r = a1[row];
  float rinv = 1.0f / sqrtf(ssArr[row] / (float)D_H + 1e-6f);
  float mq = fmaxf(__uint_as_float(mxArr[row]) * rinv, 1e-5f);
  float scale = 127.0f / mq;
  const short* hr = h16 + (size_t)row * D_H;
  int acc[10] = {0, 0, 0, 0, 0, 0, 0, 0, 0, 0};
#pragma unroll
  for (int c = 0; c < 8; ++c) {
    int k0 = c * 512 + lane * 8;
    short8 v = *(const short8*)(hr + k0);
    f32x4 b1a = *(const f32x4*)(b1 + k0);
    f32x4 b1b = *(const f32x4*)(b1 + k0 + 4);
    int tq[8];
#pragma unroll
    for (int j = 0; j < 8; ++j) {
      float fi = (float)(int)v[j];
      float bb = (j < 4) ? b1a[j] : b1b[j - 4];
      float t = fmaxf(__builtin_fmaf(fi, a1r, bb), 0.f);   // == epilogue t exactly
      float xn = t * rinv;
      float tf = rintf(xn * scale);
      tf = fminf(fmaxf(tf, -128.f), 127.f);
      tq[j] = (int)tf;
    }
    int tp0 = (tq[0] & 255) | ((tq[1] & 255) << 8) | ((tq[2] & 255) << 16) | (tq[3] << 24);
    int tp1 = (tq[4] & 255) | ((tq[5] & 255) << 8) | ((tq[6] & 255) << 16) | (tq[7] << 24);
    int k4 = c * 128 + lane * 2;
#pragma unroll
    for (int j = 0; j < 10; ++j) {
      int2v wv = *(const int2v*)&w2s[j * 1024 + k4];      // ds_read_b64
#if __has_builtin(__builtin_amdgcn_sdot4)
      acc[j] = __builtin_amdgcn_sdot4(tp0, wv[0], acc[j], false);
      acc[j] = __builtin_amdgcn_sdot4(tp1, wv[1], acc[j], false);
#else
#pragma unroll
      for (int b = 0; b < 4; ++b) {
        acc[j] += tq[b]     * (int)(signed char)((unsigned)wv[0] >> (8 * b));
        acc[j] += tq[4 + b] * (int)(signed char)((unsigned)wv[1] >> (8 * b));
      }
#endif
    }
  }
#pragma unroll
  for (int j = 0; j < 10; ++j)
#pragma unroll
    for (int off = 32; off; off >>= 1)
      acc[j] += __shfl_xor(acc[j], off);
  if (lane < 10) {
    float mw = fmaxf((float)(sums[1] / (double)(D_OUT * D_H)), 1e-5f);
    float wdeq = 1.0f / (1.0f / mw);
    int seli = 0;
#pragma unroll
    for (int j = 0; j < 10; ++j) seli = (lane == j) ? acc[j] : seli;  // static-index select
    float sel = (float)seli;          // exact: |sum| < 2^24
    out[(size_t)row * D_OUT + lane] = sel * (1.0f / scale) * wdeq + b2[lane];
  }
}

extern "C" void kernel_launch(void* const* d_in, const int* in_sizes, int n_in,
                              void* d_out, int out_size, void* d_ws, size_t ws_size,
                              hipStream_t stream) {
  const float* x  = (const float*)d_in[0];
  const float* w1 = (const float*)d_in[1];
  const float* b1 = (const float*)d_in[2];
  const float* w2 = (const float*)d_in[3];
  const float* b2 = (const float*)d_in[4];
  float* out = (float*)d_out;

  char* p = (char*)d_ws;
  double* sums        = (double*)p;
  float* a1           = (float*)(p + 256);
  float* ssArr        = (float*)(p + 65792);
  unsigned int* mxArr = (unsigned int*)(p + 131328);
  int* w2t            = (int*)(p + 196864);
  signed char* w1q    = (signed char*)(p + 262400);
  signed char* xq8    = (signed char*)(p + 3670272);
  short* h16          = (short*)(p + FIXED_BYTES);

  // size the h chunk from the ACTUAL workspace (round to multiple of 128 rows)
  size_t avail = (ws_size > FIXED_BYTES) ? ws_size - FIXED_BYTES : 0;
  int rpc = (int)(avail / ((size_t)D_H * sizeof(short)));
  rpc = (rpc / 128) * 128;
  if (rpc > MROWS) rpc = MROWS;
  if (rpc < 128) rpc = 128;

  hipMemsetAsync(sums, 0, 16, stream);
  hipMemsetAsync(p + 65792, 0, 131072, stream);   // ss + mx
  kAbsSum<<<1024, 256, 0, stream>>>(w1, D_H * D_IN, &sums[0]);
  kAbsSum<<<64, 256, 0, stream>>>(w2, D_OUT * D_H, &sums[1]);
  kQuantW1<<<D_H / 4, 256, 0, stream>>>(w1, w1q, sums);
  kQuantW2<<<40, 256, 0, stream>>>(w2, w2t, sums);
  kQuantX<<<MROWS / 4, 256, 0, stream>>>(x, xq8, a1, sums);

  for (int r0 = 0; r0 < MROWS; r0 += rpc) {
    int rc = (MROWS - r0 < rpc) ? (MROWS - r0) : rpc;   // multiple of 128
    kGemm1<<<(rc / 128) * (D_H / 128), 256, 0, stream>>>(
        xq8 + (size_t)r0 * KP1, w1q, a1 + r0, b1, ssArr + r0, mxArr + r0, h16);
    kLayer2<<<rc / 16, 1024, 0, stream>>>(h16, a1 + r0, ssArr + r0, mxArr + r0,
                                          b1, w2t, b2, sums, out + (size_t)r0 * D_OUT);
  }
}